// Round 14
// baseline (2176.445 us; speedup 1.0000x reference)
//
#include <hip/hip_runtime.h>
#include <hip/hip_bf16.h>
#include <math.h>

#define F 128
#define C 300
#define CKP 320
#define NKT 10        // CKP/32 k-steps
#define K2F 256
#define N0_ 409600
#define N1_ 40960
#define N2_ 4096
#define E0_ 409600
#define E1_ 40960
#define CAP 64
#define LDA 40        // u16 row stride of conv LDS tiles

typedef unsigned short u16;
typedef unsigned int u32;
typedef __attribute__((ext_vector_type(2))) unsigned int u32x2;
typedef __attribute__((ext_vector_type(8))) short short8;
typedef __attribute__((ext_vector_type(8))) unsigned short u16x8;
typedef __attribute__((ext_vector_type(4))) float f32x4;

__device__ __forceinline__ float lrelu(float x) { return x > 0.f ? x : 0.01f * x; }

__device__ __forceinline__ u16 f2bf(float x) {
  __hip_bfloat16 h = __float2bfloat16(x);
  u16 r; __builtin_memcpy(&r, &h, 2); return r;
}
__device__ __forceinline__ float bf2f(u16 v) {
  union { u32 u; float f; } c; c.u = ((u32)v) << 16; return c.f;
}

#define GLOAD_LDS16(gp, lp) \
  __builtin_amdgcn_global_load_lds( \
      (const __attribute__((address_space(1))) void*)(const void*)(gp), \
      (__attribute__((address_space(3))) void*)(lp), 16, 0, 0)

__global__ __launch_bounds__(256) void zero_kernel(float4* __restrict__ p, int n4) {
  int i = blockIdx.x * 256 + threadIdx.x;
  if (i < n4) p[i] = make_float4(0.f, 0.f, 0.f, 0.f);
}

__global__ __launch_bounds__(256) void convert_all(
    const float* __restrict__ Wp0, const float* __restrict__ Wp1,
    const float* __restrict__ Wp2, const float* __restrict__ Wc0,
    const float* __restrict__ Wc1,
    u16* __restrict__ Wpb0, u16* __restrict__ Wpb1, u16* __restrict__ Wpb2,
    u16* __restrict__ Wcb0, u16* __restrict__ Wcb1)
{
  int i = blockIdx.x * 256 + threadIdx.x;
  const int P = F * CKP, Q = F * K2F;
  const float* W; u16* O; int K, KP, j;
  if      (i < P)         { W = Wp0; O = Wpb0; K = C;   KP = CKP; j = i; }
  else if (i < 2 * P)     { W = Wp1; O = Wpb1; K = C;   KP = CKP; j = i - P; }
  else if (i < 3 * P)     { W = Wp2; O = Wpb2; K = C;   KP = CKP; j = i - 2 * P; }
  else if (i < 3 * P + Q) { W = Wc0; O = Wcb0; K = K2F; KP = K2F; j = i - 3 * P; }
  else if (i < 3 * P + 2 * Q) { W = Wc1; O = Wcb1; K = K2F; KP = K2F; j = i - 3 * P - Q; }
  else return;
  int f = j / KP, k = j - f * KP;
  O[j] = (k < K) ? f2bf(W[(size_t)f * K + k]) : (u16)0;
}

__global__ __launch_bounds__(256) void build_csr(
    const int* __restrict__ b0s, const int* __restrict__ b0d,
    const int* __restrict__ b1s, const int* __restrict__ b1d,
    int* __restrict__ deg0, int* __restrict__ deg1,
    int* __restrict__ csr0, int* __restrict__ csr1)
{
  int e = blockIdx.x * 256 + threadIdx.x;
  if (e < E0_) {
    int d = b0d[e];
    int slot = atomicAdd(&deg0[d], 1);
    if (slot < CAP) csr0[(size_t)d * CAP + slot] = b0s[e];
  } else {
    int e1 = e - E0_;
    if (e1 < E1_) {
      int d = b1d[e1];
      int slot = atomicAdd(&deg1[d], 1);
      if (slot < CAP) csr1[(size_t)d * CAP + slot] = b1s[e1];
    }
  }
}

struct Afrag { float4 x00, x01, x10, x11; };

// ---------- REAL embed (R8 champion structure, unchanged) ----------
__global__ __launch_bounds__(256, 2) void embed_all(
    const float* __restrict__ content0, const float* __restrict__ content1,
    const float* __restrict__ content2,
    const u16* __restrict__ Wpb0, const u16* __restrict__ Wpb1,
    const u16* __restrict__ Wpb2,
    const float* __restrict__ bp0, const float* __restrict__ bp1,
    const float* __restrict__ bp2,
    const int* __restrict__ nid0, const int* __restrict__ nid1,
    const int* __restrict__ nid2,
    const float* __restrict__ emb,
    u16* __restrict__ out0, u16* __restrict__ out1, u16* __restrict__ out2)
{
  __shared__ u16 Bs[NKT * 128 * 32];
  const int t = threadIdx.x, lane = t & 63, w = t >> 6;
  const int b = blockIdx.x;

  const float* content; const u16* Wpb; const float* bp; const int* nid;
  u16* out; int ostride, row0;
  if (b < N0_ / 128) {
    content = content0; Wpb = Wpb0; bp = bp0; nid = nid0;
    out = out0; ostride = F; row0 = b * 128;
  } else if (b < N0_ / 128 + N1_ / 128) {
    content = content1; Wpb = Wpb1; bp = bp1; nid = nid1;
    out = out1; ostride = 2 * F; row0 = (b - N0_ / 128) * 128;
  } else {
    content = content2; Wpb = Wpb2; bp = bp2; nid = nid2;
    out = out2; ostride = 2 * F; row0 = (b - N0_ / 128 - N1_ / 128) * 128;
  }

  {
    const int j_in = lane >> 2, u_in = lane & 3;
#pragma unroll
    for (int cc = 0; cc < 20; ++cc) {
      int c = w * 20 + cc;
      int kt = c >> 3, j0 = (c & 7) * 16;
      int j = j0 + j_in;
      int u = u_in ^ (j & 3);
      const u16* gp = Wpb + (size_t)j * CKP + kt * 32 + u * 8;
      GLOAD_LDS16(gp, &Bs[(size_t)(kt * 128 + j0) * 32]);
    }
  }

  f32x4 acc[2][8];
#pragma unroll
  for (int fr = 0; fr < 2; ++fr)
#pragma unroll
    for (int fc = 0; fc < 8; ++fc) {
      acc[fr][fc][0] = 0.f; acc[fr][fc][1] = 0.f;
      acc[fr][fc][2] = 0.f; acc[fr][fc][3] = 0.f;
    }

  const int frow = lane & 15, g = lane >> 4;
  const float* c0p = content + (size_t)(row0 + w * 32 + frow) * C;
  const float* c1p = c0p + (size_t)16 * C;

  auto loadA = [&](int kt) -> Afrag {
    Afrag r;
    int col = kt * 32 + g * 8;
    if (kt < NKT - 1) {
      r.x00 = *(const float4*)(c0p + col); r.x01 = *(const float4*)(c0p + col + 4);
      r.x10 = *(const float4*)(c1p + col); r.x11 = *(const float4*)(c1p + col + 4);
    } else {
      float v0[8], v1[8];
#pragma unroll
      for (int i = 0; i < 8; ++i) {
        int cc = col + i;
        v0[i] = (cc < C) ? c0p[cc] : 0.f;
        v1[i] = (cc < C) ? c1p[cc] : 0.f;
      }
      r.x00 = make_float4(v0[0], v0[1], v0[2], v0[3]);
      r.x01 = make_float4(v0[4], v0[5], v0[6], v0[7]);
      r.x10 = make_float4(v1[0], v1[1], v1[2], v1[3]);
      r.x11 = make_float4(v1[4], v1[5], v1[6], v1[7]);
    }
    return r;
  };

  const int bsw = (g ^ (frow & 3)) * 8;
  auto compute = [&](const Afrag& a, int kt) {
    u16x8 a0v, a1v;
    a0v[0]=f2bf(a.x00.x); a0v[1]=f2bf(a.x00.y); a0v[2]=f2bf(a.x00.z); a0v[3]=f2bf(a.x00.w);
    a0v[4]=f2bf(a.x01.x); a0v[5]=f2bf(a.x01.y); a0v[6]=f2bf(a.x01.z); a0v[7]=f2bf(a.x01.w);
    a1v[0]=f2bf(a.x10.x); a1v[1]=f2bf(a.x10.y); a1v[2]=f2bf(a.x10.z); a1v[3]=f2bf(a.x10.w);
    a1v[4]=f2bf(a.x11.x); a1v[5]=f2bf(a.x11.y); a1v[6]=f2bf(a.x11.z); a1v[7]=f2bf(a.x11.w);
    short8 a0 = *(short8*)&a0v, a1 = *(short8*)&a1v;
#pragma unroll
    for (int fc = 0; fc < 8; ++fc) {
      short8 bfr = *(const short8*)&Bs[(size_t)(kt * 128 + fc * 16 + frow) * 32 + bsw];
      acc[0][fc] = __builtin_amdgcn_mfma_f32_16x16x32_bf16(a0, bfr, acc[0][fc], 0, 0, 0);
      acc[1][fc] = __builtin_amdgcn_mfma_f32_16x16x32_bf16(a1, bfr, acc[1][fc], 0, 0, 0);
    }
  };

  Afrag A0 = loadA(0);
  Afrag A1 = loadA(1);
  Afrag A2 = loadA(2);
  __syncthreads();
  Afrag A3 = loadA(3); compute(A0, 0);
  A0 = loadA(4);       compute(A1, 1);
  A1 = loadA(5);       compute(A2, 2);
  A2 = loadA(6);       compute(A3, 3);
  A3 = loadA(7);       compute(A0, 4);
  A0 = loadA(8);       compute(A1, 5);
  A1 = loadA(9);       compute(A2, 6);
  compute(A3, 7);
  compute(A0, 8);
  compute(A1, 9);

  float bpv[8];
#pragma unroll
  for (int fc = 0; fc < 8; ++fc) bpv[fc] = bp[fc * 16 + frow];
#pragma unroll
  for (int fr = 0; fr < 2; ++fr) {
#pragma unroll
    for (int q = 0; q < 4; ++q) {
      int n = row0 + w * 32 + fr * 16 + g * 4 + q;
      int gi = nid[n] + 1;
      const float* erow = emb + (size_t)gi * F;
      u16* orow = out + (size_t)n * ostride;
#pragma unroll
      for (int fc = 0; fc < 8; ++fc) {
        int col = fc * 16 + frow;
        float v = acc[fr][fc][q] + bpv[fc];
        orow[col] = f2bf(erow[col] + lrelu(v));
      }
    }
  }
}

// ---------- DIAGNOSTIC probes: isolate phases of the R8 structure ----------
// MODE 1: content stream only (R8 loadA pattern), REPS=5
// MODE 2: B-stage + ds_read + MFMA only (synthetic A), REPS=24
// MODE 3: epilogue only (nid + emb gather + scattered stores), REPS=12
// MODE 4: full body, REPS=4
// All write into scratch (h0b region, overwritten later by real embed_all).
template<int MODE, int REPS>
__global__ __launch_bounds__(256, 2) void embed_probe(
    const float* __restrict__ content, const u16* __restrict__ Wpb,
    const float* __restrict__ bp, const int* __restrict__ nid,
    const float* __restrict__ emb, u16* __restrict__ out)
{
  __shared__ u16 Bs[NKT * 128 * 32];   // allocated in all modes (same occupancy)
  const int t = threadIdx.x, lane = t & 63, w = t >> 6;
  const int row0 = blockIdx.x * 128;
  const int frow = lane & 15, g = lane >> 4;
  const int bsw = (g ^ (frow & 3)) * 8;

  if constexpr (MODE == 2 || MODE == 4) {
    const int j_in = lane >> 2, u_in = lane & 3;
#pragma unroll
    for (int cc = 0; cc < 20; ++cc) {
      int c = w * 20 + cc;
      int kt = c >> 3, j0 = (c & 7) * 16;
      int j = j0 + j_in;
      int u = u_in ^ (j & 3);
      const u16* gp = Wpb + (size_t)j * CKP + kt * 32 + u * 8;
      GLOAD_LDS16(gp, &Bs[(size_t)(kt * 128 + j0) * 32]);
    }
    __syncthreads();
  }

  float keep = 0.f;
  float bpv[8];
#pragma unroll
  for (int fc = 0; fc < 8; ++fc) bpv[fc] = bp[fc * 16 + frow];

  for (int rep = 0; rep < REPS; ++rep) {
    int zo = 0;
    asm volatile("" : "+v"(zo));           // opaque 0: defeats cross-rep CSE/hoist
    const float* c0p = content + (size_t)(row0 + w * 32 + frow) * C + zo;
    const float* c1p = c0p + (size_t)16 * C;

    auto loadA = [&](int kt) -> Afrag {
      Afrag r;
      int col = kt * 32 + g * 8;
      if (kt < NKT - 1) {
        r.x00 = *(const float4*)(c0p + col); r.x01 = *(const float4*)(c0p + col + 4);
        r.x10 = *(const float4*)(c1p + col); r.x11 = *(const float4*)(c1p + col + 4);
      } else {
        float v0[8], v1[8];
#pragma unroll
        for (int i = 0; i < 8; ++i) {
          int cc = col + i;
          v0[i] = (cc < C) ? c0p[cc] : 0.f;
          v1[i] = (cc < C) ? c1p[cc] : 0.f;
        }
        r.x00 = make_float4(v0[0], v0[1], v0[2], v0[3]);
        r.x01 = make_float4(v0[4], v0[5], v0[6], v0[7]);
        r.x10 = make_float4(v1[0], v1[1], v1[2], v1[3]);
        r.x11 = make_float4(v1[4], v1[5], v1[6], v1[7]);
      }
      return r;
    };

    if constexpr (MODE == 1) {
      float s = 0.f;
#pragma unroll
      for (int kt = 0; kt < NKT; ++kt) {
        Afrag a = loadA(kt);
        s += a.x00.x + a.x00.y + a.x00.z + a.x00.w
           + a.x01.x + a.x01.y + a.x01.z + a.x01.w
           + a.x10.x + a.x10.y + a.x10.z + a.x10.w
           + a.x11.x + a.x11.y + a.x11.z + a.x11.w;
      }
      keep += s;
    } else if constexpr (MODE == 2) {
      u16x8 av;
#pragma unroll
      for (int q = 0; q < 8; ++q) av[q] = (u16)(zo + lane + q);
      short8 a0 = *(short8*)&av;
      f32x4 acc[2][8];
#pragma unroll
      for (int fr = 0; fr < 2; ++fr)
#pragma unroll
        for (int fc = 0; fc < 8; ++fc) {
          acc[fr][fc][0]=0.f; acc[fr][fc][1]=0.f; acc[fr][fc][2]=0.f; acc[fr][fc][3]=0.f;
        }
#pragma unroll
      for (int kt = 0; kt < NKT; ++kt) {
#pragma unroll
        for (int fc = 0; fc < 8; ++fc) {
          short8 bfr = *(const short8*)&Bs[(size_t)(kt * 128 + fc * 16 + frow) * 32 + bsw];
          acc[0][fc] = __builtin_amdgcn_mfma_f32_16x16x32_bf16(a0, bfr, acc[0][fc], 0, 0, 0);
          acc[1][fc] = __builtin_amdgcn_mfma_f32_16x16x32_bf16(a0, bfr, acc[1][fc], 0, 0, 0);
        }
      }
#pragma unroll
      for (int fr = 0; fr < 2; ++fr)
#pragma unroll
        for (int fc = 0; fc < 8; ++fc)
          keep += acc[fr][fc][0] + acc[fr][fc][1] + acc[fr][fc][2] + acc[fr][fc][3];
    } else if constexpr (MODE == 3) {
      float sv = (float)(zo + lane) * 0.001f;
#pragma unroll
      for (int fr = 0; fr < 2; ++fr) {
#pragma unroll
        for (int q = 0; q < 4; ++q) {
          int n = row0 + w * 32 + fr * 16 + g * 4 + q;
          int gi = nid[n] + 1;
          const float* erow = emb + (size_t)gi * F;
          u16* orow = out + (size_t)n * F;
#pragma unroll
          for (int fc = 0; fc < 8; ++fc) {
            int col = fc * 16 + frow;
            orow[col] = f2bf(erow[col] + lrelu(sv + bpv[fc]));
          }
        }
      }
    } else {  // MODE 4: full body
      f32x4 acc[2][8];
#pragma unroll
      for (int fr = 0; fr < 2; ++fr)
#pragma unroll
        for (int fc = 0; fc < 8; ++fc) {
          acc[fr][fc][0]=0.f; acc[fr][fc][1]=0.f; acc[fr][fc][2]=0.f; acc[fr][fc][3]=0.f;
        }
      auto compute = [&](const Afrag& a, int kt) {
        u16x8 a0v, a1v;
        a0v[0]=f2bf(a.x00.x); a0v[1]=f2bf(a.x00.y); a0v[2]=f2bf(a.x00.z); a0v[3]=f2bf(a.x00.w);
        a0v[4]=f2bf(a.x01.x); a0v[5]=f2bf(a.x01.y); a0v[6]=f2bf(a.x01.z); a0v[7]=f2bf(a.x01.w);
        a1v[0]=f2bf(a.x10.x); a1v[1]=f2bf(a.x10.y); a1v[2]=f2bf(a.x10.z); a1v[3]=f2bf(a.x10.w);
        a1v[4]=f2bf(a.x11.x); a1v[5]=f2bf(a.x11.y); a1v[6]=f2bf(a.x11.z); a1v[7]=f2bf(a.x11.w);
        short8 a0 = *(short8*)&a0v, a1 = *(short8*)&a1v;
#pragma unroll
        for (int fc = 0; fc < 8; ++fc) {
          short8 bfr = *(const short8*)&Bs[(size_t)(kt * 128 + fc * 16 + frow) * 32 + bsw];
          acc[0][fc] = __builtin_amdgcn_mfma_f32_16x16x32_bf16(a0, bfr, acc[0][fc], 0, 0, 0);
          acc[1][fc] = __builtin_amdgcn_mfma_f32_16x16x32_bf16(a1, bfr, acc[1][fc], 0, 0, 0);
        }
      };
      Afrag A0 = loadA(0);
      Afrag A1 = loadA(1);
      Afrag A2 = loadA(2);
      Afrag A3 = loadA(3); compute(A0, 0);
      A0 = loadA(4);       compute(A1, 1);
      A1 = loadA(5);       compute(A2, 2);
      A2 = loadA(6);       compute(A3, 3);
      A3 = loadA(7);       compute(A0, 4);
      A0 = loadA(8);       compute(A1, 5);
      A1 = loadA(9);       compute(A2, 6);
      compute(A3, 7);
      compute(A0, 8);
      compute(A1, 9);
#pragma unroll
      for (int fr = 0; fr < 2; ++fr) {
#pragma unroll
        for (int q = 0; q < 4; ++q) {
          int n = row0 + w * 32 + fr * 16 + g * 4 + q;
          int gi = nid[n] + 1;
          const float* erow = emb + (size_t)gi * F;
          u16* orow = out + (size_t)n * F;
#pragma unroll
          for (int fc = 0; fc < 8; ++fc) {
            int col = fc * 16 + frow;
            orow[col] = f2bf(erow[col] + lrelu(acc[fr][fc][q] + bpv[fc]));
          }
        }
      }
    }
    asm volatile("" ::: "memory");
  }

  if constexpr (MODE == 1 || MODE == 2) {
    ((float*)out)[(size_t)blockIdx.x * 256 + t] = keep;
  }
}

// per dst d: xa = (sum_{src} hsrc[src] - h_self) / max(deg-1,1), bf16 into xcat[d][128:256]
__global__ __launch_bounds__(256) void gather_xa(
    const u16* __restrict__ hsrc, const int* __restrict__ csr,
    const int* __restrict__ deg, u16* __restrict__ xcat)
{
  int d = blockIdx.x * 4 + (threadIdx.x >> 6);
  int lane = threadIdx.x & 63;
  u32 hv = *(const u32*)&xcat[(size_t)d * (2 * F) + lane * 2];
  float h0f = bf2f((u16)(hv & 0xffff)), h1f = bf2f((u16)(hv >> 16));
  int dg = deg[d];
  int n = dg < CAP ? dg : CAP;
  const int* cp = csr + (size_t)d * CAP;
  float s0 = 0.f, s1 = 0.f;
  int j = 0;
  for (; j + 4 <= n; j += 4) {
    int i0 = cp[j], i1 = cp[j + 1], i2 = cp[j + 2], i3 = cp[j + 3];
    u32 v0 = *(const u32*)&hsrc[(size_t)i0 * F + lane * 2];
    u32 v1 = *(const u32*)&hsrc[(size_t)i1 * F + lane * 2];
    u32 v2 = *(const u32*)&hsrc[(size_t)i2 * F + lane * 2];
    u32 v3 = *(const u32*)&hsrc[(size_t)i3 * F + lane * 2];
    s0 += bf2f((u16)(v0 & 0xffff)) + bf2f((u16)(v1 & 0xffff))
        + bf2f((u16)(v2 & 0xffff)) + bf2f((u16)(v3 & 0xffff));
    s1 += bf2f((u16)(v0 >> 16)) + bf2f((u16)(v1 >> 16))
        + bf2f((u16)(v2 >> 16)) + bf2f((u16)(v3 >> 16));
  }
  for (; j < n; ++j) {
    u32 v = *(const u32*)&hsrc[(size_t)cp[j] * F + lane * 2];
    s0 += bf2f((u16)(v & 0xffff));
    s1 += bf2f((u16)(v >> 16));
  }
  float inv = 1.f / fmaxf((float)dg - 1.f, 1.f);
  u16 a0 = f2bf((s0 - h0f) * inv), a1 = f2bf((s1 - h1f) * inv);
  *(u32*)&xcat[(size_t)d * (2 * F) + F + lane * 2] = ((u32)a1 << 16) | a0;
}

// out[n] = normalize(lrelu(xcat[n,:] @ Wc.T + bc));  xcat bf16 [n][256]
template<int F32OUT>
__global__ __launch_bounds__(256) void conv_mfma(
    const u16* __restrict__ xcat, const u16* __restrict__ Wcb,
    const float* __restrict__ bc, u16* __restrict__ outb,
    float* __restrict__ outf)
{
  __shared__ u16 As[128][LDA];
  __shared__ u16 Bs[128][LDA];
  const int t = threadIdx.x;
  const int lane = t & 63, w = t >> 6;
  const int row0 = blockIdx.x * 128;

  f32x4 acc[2][8];
#pragma unroll
  for (int fr = 0; fr < 2; ++fr)
#pragma unroll
    for (int fc = 0; fc < 8; ++fc) {
      acc[fr][fc][0] = 0.f; acc[fr][fc][1] = 0.f;
      acc[fr][fc][2] = 0.f; acc[fr][fc][3] = 0.f;
    }

  for (int k0 = 0; k0 < K2F; k0 += 32) {
    if (k0) __syncthreads();
#pragma unroll
    for (int it = 0; it < 2; ++it) {
      int cc = it * 256 + t;
      int r = cc >> 2, kc = (cc & 3) * 8;
      *(u16x8*)&As[r][kc] = *(const u16x8*)&xcat[(size_t)(row0 + r) * K2F + k0 + kc];
      *(u16x8*)&Bs[r][kc] = *(const u16x8*)&Wcb[(size_t)r * K2F + k0 + kc];
    }
    __syncthreads();

    const int frow = lane & 15;
    const int kc = (lane >> 4) * 8;
    short8 a0 = *(const short8*)&As[w * 32 + frow][kc];
    short8 a1 = *(const short8*)&As[w * 32 + 16 + frow][kc];
#pragma unroll
    for (int fc = 0; fc < 8; ++fc) {
      short8 b = *(const short8*)&Bs[fc * 16 + frow][kc];
      acc[0][fc] = __builtin_amdgcn_mfma_f32_16x16x32_bf16(a0, b, acc[0][fc], 0, 0, 0);
      acc[1][fc] = __builtin_amdgcn_mfma_f32_16x16x32_bf16(a1, b, acc[1][fc], 0, 0, 0);
    }
  }

  float bcv[8];
#pragma unroll
  for (int fc = 0; fc < 8; ++fc) bcv[fc] = bc[fc * 16 + (lane & 15)];
#pragma unroll
  for (int fr = 0; fr < 2; ++fr) {
#pragma unroll
    for (int q = 0; q < 4; ++q) {
      float x[8];
      float ss = 0.f;
#pragma unroll
      for (int fc = 0; fc < 8; ++fc) {
        x[fc] = lrelu(acc[fr][fc][q] + bcv[fc]);
        ss += x[fc] * x[fc];
      }
#pragma unroll
      for (int m = 8; m >= 1; m >>= 1) ss += __shfl_xor(ss, m, 64);
      float nrm = 1.f / fmaxf(sqrtf(ss), 1e-6f);
      int n = row0 + w * 32 + fr * 16 + (lane >> 4) * 4 + q;
#pragma unroll
      for (int fc = 0; fc < 8; ++fc) {
        int col = fc * 16 + (lane & 15);
        if (F32OUT) outf[(size_t)n * F + col] = x[fc] * nrm;
        else        outb[(size_t)n * F + col] = f2bf(x[fc] * nrm);
      }
    }
  }
}

extern "C" void kernel_launch(void* const* d_in, const int* in_sizes, int n_in,
                              void* d_out, int out_size, void* d_ws, size_t ws_size,
                              hipStream_t stream) {
  const int*   nid0     = (const int*)d_in[0];
  const int*   nid1     = (const int*)d_in[1];
  const int*   nid2     = (const int*)d_in[2];
  const float* content0 = (const float*)d_in[3];
  const float* content1 = (const float*)d_in[4];
  const float* content2 = (const float*)d_in[5];
  const int*   b0s      = (const int*)d_in[6];
  const int*   b0d      = (const int*)d_in[7];
  const int*   b1s      = (const int*)d_in[8];
  const int*   b1d      = (const int*)d_in[9];
  const float* emb      = (const float*)d_in[10];
  const float* Wp0      = (const float*)d_in[11];
  const float* bp0      = (const float*)d_in[12];
  const float* Wp1      = (const float*)d_in[13];
  const float* bp1      = (const float*)d_in[14];
  const float* Wp2      = (const float*)d_in[15];
  const float* bp2      = (const float*)d_in[16];
  const float* Wc0      = (const float*)d_in[17];
  const float* bc0      = (const float*)d_in[18];
  const float* Wc1      = (const float*)d_in[19];
  const float* bc1      = (const float*)d_in[20];

  u16* wsu = (u16*)d_ws;
  u16* h0b   = wsu;                               // N0*F bf16 (also probe scratch)
  u16* xcat1 = h0b + (size_t)N0_ * F;
  u16* xcat2 = xcat1 + (size_t)N1_ * 2 * F;
  u16* h1nb  = xcat2 + (size_t)N2_ * 2 * F;
  u16* Wpb0  = h1nb + (size_t)N1_ * F;
  u16* Wpb1  = Wpb0 + (size_t)F * CKP;
  u16* Wpb2  = Wpb1 + (size_t)F * CKP;
  u16* Wcb0  = Wpb2 + (size_t)F * CKP;
  u16* Wcb1  = Wcb0 + (size_t)F * K2F;
  int* deg0  = (int*)(Wcb1 + (size_t)F * K2F);
  int* deg1  = deg0 + N1_;
  int* csr0  = deg1 + N2_;
  int* csr1  = csr0 + (size_t)N1_ * CAP;

  const int zn4 = (N1_ + N2_) / 4;
  zero_kernel<<<(zn4 + 255) / 256, 256, 0, stream>>>((float4*)deg0, zn4);

  build_csr<<<(E0_ + E1_ + 255) / 256, 256, 0, stream>>>(
      b0s, b0d, b1s, b1d, deg0, deg1, csr0, csr1);

  convert_all<<<(3 * F * CKP + 2 * F * K2F + 255) / 256, 256, 0, stream>>>(
      Wp0, Wp1, Wp2, Wc0, Wc1, Wpb0, Wpb1, Wpb2, Wcb0, Wcb1);

  // ---- diagnostic probes (write into h0b scratch; overwritten below) ----
  embed_probe<1, 5><<<N0_ / 128, 256, 0, stream>>>(content0, Wpb0, bp0, nid0, emb, h0b);
  embed_probe<2, 24><<<N0_ / 128, 256, 0, stream>>>(content0, Wpb0, bp0, nid0, emb, h0b);
  embed_probe<3, 12><<<N0_ / 128, 256, 0, stream>>>(content0, Wpb0, bp0, nid0, emb, h0b);
  embed_probe<4, 4><<<N0_ / 128, 256, 0, stream>>>(content0, Wpb0, bp0, nid0, emb, h0b);

  embed_all<<<(N0_ + N1_ + N2_) / 128, 256, 0, stream>>>(
      content0, content1, content2, Wpb0, Wpb1, Wpb2,
      bp0, bp1, bp2, nid0, nid1, nid2, emb, h0b, xcat1, xcat2);

  gather_xa<<<N1_ / 4, 256, 0, stream>>>(h0b, csr0, deg0, xcat1);
  conv_mfma<0><<<N1_ / 128, 256, 0, stream>>>(xcat1, Wcb0, bc0, h1nb, nullptr);

  gather_xa<<<N2_ / 4, 256, 0, stream>>>(h1nb, csr1, deg1, xcat2);
  conv_mfma<1><<<N2_ / 128, 256, 0, stream>>>(xcat2, Wcb1, bc1, nullptr, (float*)d_out);
}

// Round 15
// 528.036 us; speedup vs baseline: 4.1218x; 4.1218x over previous
//
#include <hip/hip_runtime.h>
#include <hip/hip_bf16.h>
#include <math.h>

#define F 128
#define C 300
#define CKP 320
#define NKT 10        // CKP/32 k-steps
#define K2F 256
#define N0_ 409600
#define N1_ 40960
#define N2_ 4096
#define E0_ 409600
#define E1_ 40960
#define CAP 64
#define LDA 40        // u16 row stride of conv LDS tiles

typedef unsigned short u16;
typedef unsigned int u32;
typedef __attribute__((ext_vector_type(2))) unsigned int u32x2;
typedef __attribute__((ext_vector_type(8))) short short8;
typedef __attribute__((ext_vector_type(8))) unsigned short u16x8;
typedef __attribute__((ext_vector_type(4))) float f32x4;

__device__ __forceinline__ float lrelu(float x) { return x > 0.f ? x : 0.01f * x; }

__device__ __forceinline__ u16 f2bf(float x) {
  __hip_bfloat16 h = __float2bfloat16(x);
  u16 r; __builtin_memcpy(&r, &h, 2); return r;
}
__device__ __forceinline__ float bf2f(u16 v) {
  union { u32 u; float f; } c; c.u = ((u32)v) << 16; return c.f;
}

__global__ __launch_bounds__(256) void zero_kernel(float4* __restrict__ p, int n4) {
  int i = blockIdx.x * 256 + threadIdx.x;
  if (i < n4) p[i] = make_float4(0.f, 0.f, 0.f, 0.f);
}

__global__ __launch_bounds__(256) void convert_all(
    const float* __restrict__ Wp0, const float* __restrict__ Wp1,
    const float* __restrict__ Wp2, const float* __restrict__ Wc0,
    const float* __restrict__ Wc1,
    u16* __restrict__ Wpb0, u16* __restrict__ Wpb1, u16* __restrict__ Wpb2,
    u16* __restrict__ Wcb0, u16* __restrict__ Wcb1)
{
  int i = blockIdx.x * 256 + threadIdx.x;
  const int P = F * CKP, Q = F * K2F;
  const float* W; u16* O; int K, KP, j;
  if      (i < P)         { W = Wp0; O = Wpb0; K = C;   KP = CKP; j = i; }
  else if (i < 2 * P)     { W = Wp1; O = Wpb1; K = C;   KP = CKP; j = i - P; }
  else if (i < 3 * P)     { W = Wp2; O = Wpb2; K = C;   KP = CKP; j = i - 2 * P; }
  else if (i < 3 * P + Q) { W = Wc0; O = Wcb0; K = K2F; KP = K2F; j = i - 3 * P; }
  else if (i < 3 * P + 2 * Q) { W = Wc1; O = Wcb1; K = K2F; KP = K2F; j = i - 3 * P - Q; }
  else return;
  int f = j / KP, k = j - f * KP;
  O[j] = (k < K) ? f2bf(W[(size_t)f * K + k]) : (u16)0;
}

__global__ __launch_bounds__(256) void build_csr(
    const int* __restrict__ b0s, const int* __restrict__ b0d,
    const int* __restrict__ b1s, const int* __restrict__ b1d,
    int* __restrict__ deg0, int* __restrict__ deg1,
    int* __restrict__ csr0, int* __restrict__ csr1)
{
  int e = blockIdx.x * 256 + threadIdx.x;
  if (e < E0_) {
    int d = b0d[e];
    int slot = atomicAdd(&deg0[d], 1);
    if (slot < CAP) csr0[(size_t)d * CAP + slot] = b0s[e];
  } else {
    int e1 = e - E0_;
    if (e1 < E1_) {
      int d = b1d[e1];
      int slot = atomicAdd(&deg1[d], 1);
      if (slot < CAP) csr1[(size_t)d * CAP + slot] = b1s[e1];
    }
  }
}

struct A16 { float4 x0, x1; };

// Fused embed, NO LDS (P14 ablation: phases are BW-bound at occupancy; the
// 80KB B-LDS capped us at 2 blocks/CU). B (80KB) is L2-resident — fragments
// loaded global->reg per kt. One 16-row fragment per wave, 64 rows/block,
// zero barriers, dist-3 content prefetch, R8 epilogue.
__global__ __launch_bounds__(256, 4) void embed_all(
    const float* __restrict__ content0, const float* __restrict__ content1,
    const float* __restrict__ content2,
    const u16* __restrict__ Wpb0, const u16* __restrict__ Wpb1,
    const u16* __restrict__ Wpb2,
    const float* __restrict__ bp0, const float* __restrict__ bp1,
    const float* __restrict__ bp2,
    const int* __restrict__ nid0, const int* __restrict__ nid1,
    const int* __restrict__ nid2,
    const float* __restrict__ emb,
    u16* __restrict__ out0, u16* __restrict__ out1, u16* __restrict__ out2)
{
  const int t = threadIdx.x, lane = t & 63, w = t >> 6;
  const int b = blockIdx.x;

  const float* content; const u16* Wpb; const float* bp; const int* nid;
  u16* out; int ostride, rowb;
  if (b < N0_ / 64) {
    content = content0; Wpb = Wpb0; bp = bp0; nid = nid0;
    out = out0; ostride = F; rowb = b * 64;
  } else if (b < N0_ / 64 + N1_ / 64) {
    content = content1; Wpb = Wpb1; bp = bp1; nid = nid1;
    out = out1; ostride = 2 * F; rowb = (b - N0_ / 64) * 64;
  } else {
    content = content2; Wpb = Wpb2; bp = bp2; nid = nid2;
    out = out2; ostride = 2 * F; rowb = (b - N0_ / 64 - N1_ / 64) * 64;
  }

  const int frow = lane & 15, g = lane >> 4;
  const int row0 = rowb + w * 16;                 // this wave's 16 rows
  const float* c0p = content + (size_t)(row0 + frow) * C;
  const u16* bbase = Wpb + (size_t)frow * CKP + g * 8;   // + fc*16*CKP + kt*32

  f32x4 acc[8];
#pragma unroll
  for (int fc = 0; fc < 8; ++fc) {
    acc[fc][0] = 0.f; acc[fc][1] = 0.f; acc[fc][2] = 0.f; acc[fc][3] = 0.f;
  }

  auto loadA = [&](int kt) -> A16 {
    A16 r;
    int col = kt * 32 + g * 8;
    if (kt < NKT - 1) {
      r.x0 = *(const float4*)(c0p + col);
      r.x1 = *(const float4*)(c0p + col + 4);
    } else {                                // K tail: cols 288..319, valid < 300
      float v[8];
#pragma unroll
      for (int i = 0; i < 8; ++i) {
        int cc = col + i;
        v[i] = (cc < C) ? c0p[cc] : 0.f;
      }
      r.x0 = make_float4(v[0], v[1], v[2], v[3]);
      r.x1 = make_float4(v[4], v[5], v[6], v[7]);
    }
    return r;
  };

  auto compute = [&](const A16& a, int kt) {
    u16x8 av;
    av[0]=f2bf(a.x0.x); av[1]=f2bf(a.x0.y); av[2]=f2bf(a.x0.z); av[3]=f2bf(a.x0.w);
    av[4]=f2bf(a.x1.x); av[5]=f2bf(a.x1.y); av[6]=f2bf(a.x1.z); av[7]=f2bf(a.x1.w);
    short8 a0 = *(short8*)&av;
#pragma unroll
    for (int fc = 0; fc < 8; ++fc) {
      short8 bfr = *(const short8*)(bbase + (size_t)(fc * 16) * CKP + kt * 32);
      acc[fc] = __builtin_amdgcn_mfma_f32_16x16x32_bf16(a0, bfr, acc[fc], 0, 0, 0);
    }
  };

  // distance-3 static content prefetch, no barriers anywhere
  A16 A0 = loadA(0);
  A16 A1 = loadA(1);
  A16 A2 = loadA(2);
  A16 A3 = loadA(3); compute(A0, 0);
  A0 = loadA(4);     compute(A1, 1);
  A1 = loadA(5);     compute(A2, 2);
  A2 = loadA(6);     compute(A3, 3);
  A3 = loadA(7);     compute(A0, 4);
  A0 = loadA(8);     compute(A1, 5);
  A1 = loadA(9);     compute(A2, 6);
  compute(A3, 7);
  compute(A0, 8);
  compute(A1, 9);

  // R8-style epilogue (one fragment): lane writes rows g*4+q, cols fc*16+frow
  float bpv[8];
#pragma unroll
  for (int fc = 0; fc < 8; ++fc) bpv[fc] = bp[fc * 16 + frow];
#pragma unroll
  for (int q = 0; q < 4; ++q) {
    int n = row0 + g * 4 + q;
    int gi = nid[n] + 1;
    const float* erow = emb + (size_t)gi * F;
    u16* orow = out + (size_t)n * ostride;
#pragma unroll
    for (int fc = 0; fc < 8; ++fc) {
      int col = fc * 16 + frow;
      float v = acc[fc][q] + bpv[fc];
      orow[col] = f2bf(erow[col] + lrelu(v));
    }
  }
}

// per dst d: xa = (sum_{src} hsrc[src] - h_self) / max(deg-1,1), bf16 into xcat[d][128:256]
__global__ __launch_bounds__(256) void gather_xa(
    const u16* __restrict__ hsrc, const int* __restrict__ csr,
    const int* __restrict__ deg, u16* __restrict__ xcat)
{
  int d = blockIdx.x * 4 + (threadIdx.x >> 6);
  int lane = threadIdx.x & 63;
  u32 hv = *(const u32*)&xcat[(size_t)d * (2 * F) + lane * 2];
  float h0f = bf2f((u16)(hv & 0xffff)), h1f = bf2f((u16)(hv >> 16));
  int dg = deg[d];
  int n = dg < CAP ? dg : CAP;
  const int* cp = csr + (size_t)d * CAP;
  float s0 = 0.f, s1 = 0.f;
  int j = 0;
  for (; j + 4 <= n; j += 4) {
    int i0 = cp[j], i1 = cp[j + 1], i2 = cp[j + 2], i3 = cp[j + 3];
    u32 v0 = *(const u32*)&hsrc[(size_t)i0 * F + lane * 2];
    u32 v1 = *(const u32*)&hsrc[(size_t)i1 * F + lane * 2];
    u32 v2 = *(const u32*)&hsrc[(size_t)i2 * F + lane * 2];
    u32 v3 = *(const u32*)&hsrc[(size_t)i3 * F + lane * 2];
    s0 += bf2f((u16)(v0 & 0xffff)) + bf2f((u16)(v1 & 0xffff))
        + bf2f((u16)(v2 & 0xffff)) + bf2f((u16)(v3 & 0xffff));
    s1 += bf2f((u16)(v0 >> 16)) + bf2f((u16)(v1 >> 16))
        + bf2f((u16)(v2 >> 16)) + bf2f((u16)(v3 >> 16));
  }
  for (; j < n; ++j) {
    u32 v = *(const u32*)&hsrc[(size_t)cp[j] * F + lane * 2];
    s0 += bf2f((u16)(v & 0xffff));
    s1 += bf2f((u16)(v >> 16));
  }
  float inv = 1.f / fmaxf((float)dg - 1.f, 1.f);
  u16 a0 = f2bf((s0 - h0f) * inv), a1 = f2bf((s1 - h1f) * inv);
  *(u32*)&xcat[(size_t)d * (2 * F) + F + lane * 2] = ((u32)a1 << 16) | a0;
}

// out[n] = normalize(lrelu(xcat[n,:] @ Wc.T + bc));  xcat bf16 [n][256]
template<int F32OUT>
__global__ __launch_bounds__(256) void conv_mfma(
    const u16* __restrict__ xcat, const u16* __restrict__ Wcb,
    const float* __restrict__ bc, u16* __restrict__ outb,
    float* __restrict__ outf)
{
  __shared__ u16 As[128][LDA];
  __shared__ u16 Bs[128][LDA];
  const int t = threadIdx.x;
  const int lane = t & 63, w = t >> 6;
  const int row0 = blockIdx.x * 128;

  f32x4 acc[2][8];
#pragma unroll
  for (int fr = 0; fr < 2; ++fr)
#pragma unroll
    for (int fc = 0; fc < 8; ++fc) {
      acc[fr][fc][0] = 0.f; acc[fr][fc][1] = 0.f;
      acc[fr][fc][2] = 0.f; acc[fr][fc][3] = 0.f;
    }

  for (int k0 = 0; k0 < K2F; k0 += 32) {
    if (k0) __syncthreads();
#pragma unroll
    for (int it = 0; it < 2; ++it) {
      int cc = it * 256 + t;
      int r = cc >> 2, kc = (cc & 3) * 8;
      *(u16x8*)&As[r][kc] = *(const u16x8*)&xcat[(size_t)(row0 + r) * K2F + k0 + kc];
      *(u16x8*)&Bs[r][kc] = *(const u16x8*)&Wcb[(size_t)r * K2F + k0 + kc];
    }
    __syncthreads();

    const int frow = lane & 15;
    const int kc = (lane >> 4) * 8;
    short8 a0 = *(const short8*)&As[w * 32 + frow][kc];
    short8 a1 = *(const short8*)&As[w * 32 + 16 + frow][kc];
#pragma unroll
    for (int fc = 0; fc < 8; ++fc) {
      short8 b = *(const short8*)&Bs[fc * 16 + frow][kc];
      acc[0][fc] = __builtin_amdgcn_mfma_f32_16x16x32_bf16(a0, b, acc[0][fc], 0, 0, 0);
      acc[1][fc] = __builtin_amdgcn_mfma_f32_16x16x32_bf16(a1, b, acc[1][fc], 0, 0, 0);
    }
  }

  float bcv[8];
#pragma unroll
  for (int fc = 0; fc < 8; ++fc) bcv[fc] = bc[fc * 16 + (lane & 15)];
#pragma unroll
  for (int fr = 0; fr < 2; ++fr) {
#pragma unroll
    for (int q = 0; q < 4; ++q) {
      float x[8];
      float ss = 0.f;
#pragma unroll
      for (int fc = 0; fc < 8; ++fc) {
        x[fc] = lrelu(acc[fr][fc][q] + bcv[fc]);
        ss += x[fc] * x[fc];
      }
#pragma unroll
      for (int m = 8; m >= 1; m >>= 1) ss += __shfl_xor(ss, m, 64);
      float nrm = 1.f / fmaxf(sqrtf(ss), 1e-6f);
      int n = row0 + w * 32 + fr * 16 + (lane >> 4) * 4 + q;
#pragma unroll
      for (int fc = 0; fc < 8; ++fc) {
        int col = fc * 16 + (lane & 15);
        if (F32OUT) outf[(size_t)n * F + col] = x[fc] * nrm;
        else        outb[(size_t)n * F + col] = f2bf(x[fc] * nrm);
      }
    }
  }
}

extern "C" void kernel_launch(void* const* d_in, const int* in_sizes, int n_in,
                              void* d_out, int out_size, void* d_ws, size_t ws_size,
                              hipStream_t stream) {
  const int*   nid0     = (const int*)d_in[0];
  const int*   nid1     = (const int*)d_in[1];
  const int*   nid2     = (const int*)d_in[2];
  const float* content0 = (const float*)d_in[3];
  const float* content1 = (const float*)d_in[4];
  const float* content2 = (const float*)d_in[5];
  const int*   b0s      = (const int*)d_in[6];
  const int*   b0d      = (const int*)d_in[7];
  const int*   b1s      = (const int*)d_in[8];
  const int*   b1d      = (const int*)d_in[9];
  const float* emb      = (const float*)d_in[10];
  const float* Wp0      = (const float*)d_in[11];
  const float* bp0      = (const float*)d_in[12];
  const float* Wp1      = (const float*)d_in[13];
  const float* bp1      = (const float*)d_in[14];
  const float* Wp2      = (const float*)d_in[15];
  const float* bp2      = (const float*)d_in[16];
  const float* Wc0      = (const float*)d_in[17];
  const float* bc0      = (const float*)d_in[18];
  const float* Wc1      = (const float*)d_in[19];
  const float* bc1      = (const float*)d_in[20];

  u16* wsu = (u16*)d_ws;
  u16* h0b   = wsu;                               // N0*F bf16
  u16* xcat1 = h0b + (size_t)N0_ * F;             // N1*256 bf16 (h1 | xa1)
  u16* xcat2 = xcat1 + (size_t)N1_ * 2 * F;       // N2*256 bf16 (h2 | xa2)
  u16* h1nb  = xcat2 + (size_t)N2_ * 2 * F;       // N1*F bf16 (conv0 out)
  u16* Wpb0  = h1nb + (size_t)N1_ * F;            // F*CKP bf16 each
  u16* Wpb1  = Wpb0 + (size_t)F * CKP;
  u16* Wpb2  = Wpb1 + (size_t)F * CKP;
  u16* Wcb0  = Wpb2 + (size_t)F * CKP;            // F*K2F bf16 each
  u16* Wcb1  = Wcb0 + (size_t)F * K2F;
  int* deg0  = (int*)(Wcb1 + (size_t)F * K2F);    // N1 } zeroed together
  int* deg1  = deg0 + N1_;                        // N2 }
  int* csr0  = deg1 + N2_;                        // N1*CAP
  int* csr1  = csr0 + (size_t)N1_ * CAP;          // N2*CAP

  const int zn4 = (N1_ + N2_) / 4;
  zero_kernel<<<(zn4 + 255) / 256, 256, 0, stream>>>((float4*)deg0, zn4);

  build_csr<<<(E0_ + E1_ + 255) / 256, 256, 0, stream>>>(
      b0s, b0d, b1s, b1d, deg0, deg1, csr0, csr1);

  convert_all<<<(3 * F * CKP + 2 * F * K2F + 255) / 256, 256, 0, stream>>>(
      Wp0, Wp1, Wp2, Wc0, Wc1, Wpb0, Wpb1, Wpb2, Wcb0, Wcb1);

  embed_all<<<(N0_ + N1_ + N2_) / 64, 256, 0, stream>>>(
      content0, content1, content2, Wpb0, Wpb1, Wpb2,
      bp0, bp1, bp2, nid0, nid1, nid2, emb, h0b, xcat1, xcat2);

  gather_xa<<<N1_ / 4, 256, 0, stream>>>(h0b, csr0, deg0, xcat1);
  conv_mfma<0><<<N1_ / 128, 256, 0, stream>>>(xcat1, Wcb0, bc0, h1nb, nullptr);

  gather_xa<<<N2_ / 4, 256, 0, stream>>>(h1nb, csr1, deg1, xcat2);
  conv_mfma<1><<<N2_ / 128, 256, 0, stream>>>(xcat2, Wcb1, bc1, nullptr, (float*)d_out);
}

// Round 16
// 318.703 us; speedup vs baseline: 6.8291x; 1.6568x over previous
//
#include <hip/hip_runtime.h>
#include <hip/hip_bf16.h>
#include <math.h>

#define F 128
#define C 300
#define CKP 320
#define NKT 10        // CKP/32 k-steps
#define K2F 256
#define N0_ 409600
#define N1_ 40960
#define N2_ 4096
#define E0_ 409600
#define E1_ 40960
#define CAP 64
#define LDA 40        // u16 row stride of conv LDS tiles

typedef unsigned short u16;
typedef unsigned int u32;
typedef __attribute__((ext_vector_type(2))) unsigned int u32x2;
typedef __attribute__((ext_vector_type(8))) short short8;
typedef __attribute__((ext_vector_type(8))) unsigned short u16x8;
typedef __attribute__((ext_vector_type(4))) float f32x4;

__device__ __forceinline__ float lrelu(float x) { return x > 0.f ? x : 0.01f * x; }

__device__ __forceinline__ u16 f2bf(float x) {
  __hip_bfloat16 h = __float2bfloat16(x);
  u16 r; __builtin_memcpy(&r, &h, 2); return r;
}
__device__ __forceinline__ float bf2f(u16 v) {
  union { u32 u; float f; } c; c.u = ((u32)v) << 16; return c.f;
}

#define GLOAD_LDS16(gp, lp) \
  __builtin_amdgcn_global_load_lds( \
      (const __attribute__((address_space(1))) void*)(const void*)(gp), \
      (__attribute__((address_space(3))) void*)(lp), 16, 0, 0)

__global__ __launch_bounds__(256) void zero_kernel(float4* __restrict__ p, int n4) {
  int i = blockIdx.x * 256 + threadIdx.x;
  if (i < n4) p[i] = make_float4(0.f, 0.f, 0.f, 0.f);
}

__global__ __launch_bounds__(256) void convert_all(
    const float* __restrict__ Wp0, const float* __restrict__ Wp1,
    const float* __restrict__ Wp2, const float* __restrict__ Wc0,
    const float* __restrict__ Wc1,
    u16* __restrict__ Wpb0, u16* __restrict__ Wpb1, u16* __restrict__ Wpb2,
    u16* __restrict__ Wcb0, u16* __restrict__ Wcb1)
{
  int i = blockIdx.x * 256 + threadIdx.x;
  const int P = F * CKP, Q = F * K2F;
  const float* W; u16* O; int K, KP, j;
  if      (i < P)         { W = Wp0; O = Wpb0; K = C;   KP = CKP; j = i; }
  else if (i < 2 * P)     { W = Wp1; O = Wpb1; K = C;   KP = CKP; j = i - P; }
  else if (i < 3 * P)     { W = Wp2; O = Wpb2; K = C;   KP = CKP; j = i - 2 * P; }
  else if (i < 3 * P + Q) { W = Wc0; O = Wcb0; K = K2F; KP = K2F; j = i - 3 * P; }
  else if (i < 3 * P + 2 * Q) { W = Wc1; O = Wcb1; K = K2F; KP = K2F; j = i - 3 * P - Q; }
  else return;
  int f = j / KP, k = j - f * KP;
  O[j] = (k < K) ? f2bf(W[(size_t)f * K + k]) : (u16)0;
}

__global__ __launch_bounds__(256) void build_csr(
    const int* __restrict__ b0s, const int* __restrict__ b0d,
    const int* __restrict__ b1s, const int* __restrict__ b1d,
    int* __restrict__ deg0, int* __restrict__ deg1,
    int* __restrict__ csr0, int* __restrict__ csr1)
{
  int e = blockIdx.x * 256 + threadIdx.x;
  if (e < E0_) {
    int d = b0d[e];
    int slot = atomicAdd(&deg0[d], 1);
    if (slot < CAP) csr0[(size_t)d * CAP + slot] = b0s[e];
  } else {
    int e1 = e - E0_;
    if (e1 < E1_) {
      int d = b1d[e1];
      int slot = atomicAdd(&deg1[d], 1);
      if (slot < CAP) csr1[(size_t)d * CAP + slot] = b1s[e1];
    }
  }
}

struct Afrag { float4 x00, x01, x10, x11; };

// R8 champion structure with ONE change: 512-thread blocks (8 waves per 80KB
// B-copy) -> 2 blocks/CU = 16 waves/CU (was 8). A-prefetch depth 3->2 to fit
// the 128-reg budget of 4 waves/SIMD. Tests the occupancy/TLP hypothesis
// (R10: 4w=419us, R8: 8w=230us -> predict 16w ~125us).
__global__ __launch_bounds__(512, 4) void embed_all(
    const float* __restrict__ content0, const float* __restrict__ content1,
    const float* __restrict__ content2,
    const u16* __restrict__ Wpb0, const u16* __restrict__ Wpb1,
    const u16* __restrict__ Wpb2,
    const float* __restrict__ bp0, const float* __restrict__ bp1,
    const float* __restrict__ bp2,
    const int* __restrict__ nid0, const int* __restrict__ nid1,
    const int* __restrict__ nid2,
    const float* __restrict__ emb,
    u16* __restrict__ out0, u16* __restrict__ out1, u16* __restrict__ out2)
{
  __shared__ u16 Bs[NKT * 128 * 32];   // 80 KB: [kt][j][32], 16B units XOR-swizzled by j&3
  const int t = threadIdx.x, lane = t & 63, w = t >> 6;   // w in [0,8)
  const int b = blockIdx.x;

  const float* content; const u16* Wpb; const float* bp; const int* nid;
  u16* out; int ostride, row0;
  if (b < N0_ / 256) {
    content = content0; Wpb = Wpb0; bp = bp0; nid = nid0;
    out = out0; ostride = F; row0 = b * 256;
  } else if (b < N0_ / 256 + N1_ / 256) {
    content = content1; Wpb = Wpb1; bp = bp1; nid = nid1;
    out = out1; ostride = 2 * F; row0 = (b - N0_ / 256) * 256;
  } else {
    content = content2; Wpb = Wpb2; bp = bp2; nid = nid2;
    out = out2; ostride = 2 * F; row0 = (b - N0_ / 256 - N1_ / 256) * 256;
  }

  // ---- stage whole B once (each of 8 waves: 10 x 1KB chunks) ----
  {
    const int j_in = lane >> 2, u_in = lane & 3;
#pragma unroll
    for (int cc = 0; cc < 10; ++cc) {
      int c = w * 10 + cc;
      int kt = c >> 3, j0 = (c & 7) * 16;
      int j = j0 + j_in;
      int u = u_in ^ (j & 3);                 // pre-swizzled global source
      const u16* gp = Wpb + (size_t)j * CKP + kt * 32 + u * 8;
      GLOAD_LDS16(gp, &Bs[(size_t)(kt * 128 + j0) * 32]);
    }
  }

  f32x4 acc[2][8];
#pragma unroll
  for (int fr = 0; fr < 2; ++fr)
#pragma unroll
    for (int fc = 0; fc < 8; ++fc) {
      acc[fr][fc][0] = 0.f; acc[fr][fc][1] = 0.f;
      acc[fr][fc][2] = 0.f; acc[fr][fc][3] = 0.f;
    }

  const int frow = lane & 15, g = lane >> 4;
  const float* c0p = content + (size_t)(row0 + w * 32 + frow) * C;
  const float* c1p = c0p + (size_t)16 * C;

  auto loadA = [&](int kt) -> Afrag {
    Afrag r;
    int col = kt * 32 + g * 8;
    if (kt < NKT - 1) {
      r.x00 = *(const float4*)(c0p + col); r.x01 = *(const float4*)(c0p + col + 4);
      r.x10 = *(const float4*)(c1p + col); r.x11 = *(const float4*)(c1p + col + 4);
    } else {                                // K tail: cols 288..319, valid < 300
      float v0[8], v1[8];
#pragma unroll
      for (int i = 0; i < 8; ++i) {
        int cc = col + i;
        v0[i] = (cc < C) ? c0p[cc] : 0.f;
        v1[i] = (cc < C) ? c1p[cc] : 0.f;
      }
      r.x00 = make_float4(v0[0], v0[1], v0[2], v0[3]);
      r.x01 = make_float4(v0[4], v0[5], v0[6], v0[7]);
      r.x10 = make_float4(v1[0], v1[1], v1[2], v1[3]);
      r.x11 = make_float4(v1[4], v1[5], v1[6], v1[7]);
    }
    return r;
  };

  const int bsw = (g ^ (frow & 3)) * 8;
  auto compute = [&](const Afrag& a, int kt) {
    u16x8 a0v, a1v;
    a0v[0]=f2bf(a.x00.x); a0v[1]=f2bf(a.x00.y); a0v[2]=f2bf(a.x00.z); a0v[3]=f2bf(a.x00.w);
    a0v[4]=f2bf(a.x01.x); a0v[5]=f2bf(a.x01.y); a0v[6]=f2bf(a.x01.z); a0v[7]=f2bf(a.x01.w);
    a1v[0]=f2bf(a.x10.x); a1v[1]=f2bf(a.x10.y); a1v[2]=f2bf(a.x10.z); a1v[3]=f2bf(a.x10.w);
    a1v[4]=f2bf(a.x11.x); a1v[5]=f2bf(a.x11.y); a1v[6]=f2bf(a.x11.z); a1v[7]=f2bf(a.x11.w);
    short8 a0 = *(short8*)&a0v, a1 = *(short8*)&a1v;
#pragma unroll
    for (int fc = 0; fc < 8; ++fc) {
      short8 bfr = *(const short8*)&Bs[(size_t)(kt * 128 + fc * 16 + frow) * 32 + bsw];
      acc[0][fc] = __builtin_amdgcn_mfma_f32_16x16x32_bf16(a0, bfr, acc[0][fc], 0, 0, 0);
      acc[1][fc] = __builtin_amdgcn_mfma_f32_16x16x32_bf16(a1, bfr, acc[1][fc], 0, 0, 0);
    }
  };

  // 2-buffer dist-2 register pipeline (fits 128-reg budget), no in-loop barriers
  Afrag A0 = loadA(0);
  Afrag A1 = loadA(1);
  __syncthreads();                 // B resident from here on
  compute(A0, 0); A0 = loadA(2);
  compute(A1, 1); A1 = loadA(3);
  compute(A0, 2); A0 = loadA(4);
  compute(A1, 3); A1 = loadA(5);
  compute(A0, 4); A0 = loadA(6);
  compute(A1, 5); A1 = loadA(7);
  compute(A0, 6); A0 = loadA(8);
  compute(A1, 7); A1 = loadA(9);
  compute(A0, 8);
  compute(A1, 9);

  // ---- epilogue: bias + lrelu + emb gather, bf16 store (R8 layout) ----
  float bpv[8];
#pragma unroll
  for (int fc = 0; fc < 8; ++fc) bpv[fc] = bp[fc * 16 + frow];
#pragma unroll
  for (int fr = 0; fr < 2; ++fr) {
#pragma unroll
    for (int q = 0; q < 4; ++q) {
      int n = row0 + w * 32 + fr * 16 + g * 4 + q;
      int gi = nid[n] + 1;
      const float* erow = emb + (size_t)gi * F;
      u16* orow = out + (size_t)n * ostride;
#pragma unroll
      for (int fc = 0; fc < 8; ++fc) {
        int col = fc * 16 + frow;
        float v = acc[fr][fc][q] + bpv[fc];
        orow[col] = f2bf(erow[col] + lrelu(v));
      }
    }
  }
}

// per dst d: xa = (sum_{src} hsrc[src] - h_self) / max(deg-1,1), bf16 into xcat[d][128:256]
__global__ __launch_bounds__(256) void gather_xa(
    const u16* __restrict__ hsrc, const int* __restrict__ csr,
    const int* __restrict__ deg, u16* __restrict__ xcat)
{
  int d = blockIdx.x * 4 + (threadIdx.x >> 6);
  int lane = threadIdx.x & 63;
  u32 hv = *(const u32*)&xcat[(size_t)d * (2 * F) + lane * 2];
  float h0f = bf2f((u16)(hv & 0xffff)), h1f = bf2f((u16)(hv >> 16));
  int dg = deg[d];
  int n = dg < CAP ? dg : CAP;
  const int* cp = csr + (size_t)d * CAP;
  float s0 = 0.f, s1 = 0.f;
  int j = 0;
  for (; j + 4 <= n; j += 4) {
    int i0 = cp[j], i1 = cp[j + 1], i2 = cp[j + 2], i3 = cp[j + 3];
    u32 v0 = *(const u32*)&hsrc[(size_t)i0 * F + lane * 2];
    u32 v1 = *(const u32*)&hsrc[(size_t)i1 * F + lane * 2];
    u32 v2 = *(const u32*)&hsrc[(size_t)i2 * F + lane * 2];
    u32 v3 = *(const u32*)&hsrc[(size_t)i3 * F + lane * 2];
    s0 += bf2f((u16)(v0 & 0xffff)) + bf2f((u16)(v1 & 0xffff))
        + bf2f((u16)(v2 & 0xffff)) + bf2f((u16)(v3 & 0xffff));
    s1 += bf2f((u16)(v0 >> 16)) + bf2f((u16)(v1 >> 16))
        + bf2f((u16)(v2 >> 16)) + bf2f((u16)(v3 >> 16));
  }
  for (; j < n; ++j) {
    u32 v = *(const u32*)&hsrc[(size_t)cp[j] * F + lane * 2];
    s0 += bf2f((u16)(v & 0xffff));
    s1 += bf2f((u16)(v >> 16));
  }
  float inv = 1.f / fmaxf((float)dg - 1.f, 1.f);
  u16 a0 = f2bf((s0 - h0f) * inv), a1 = f2bf((s1 - h1f) * inv);
  *(u32*)&xcat[(size_t)d * (2 * F) + F + lane * 2] = ((u32)a1 << 16) | a0;
}

// out[n] = normalize(lrelu(xcat[n,:] @ Wc.T + bc));  xcat bf16 [n][256]
template<int F32OUT>
__global__ __launch_bounds__(256) void conv_mfma(
    const u16* __restrict__ xcat, const u16* __restrict__ Wcb,
    const float* __restrict__ bc, u16* __restrict__ outb,
    float* __restrict__ outf)
{
  __shared__ u16 As[128][LDA];
  __shared__ u16 Bs[128][LDA];
  const int t = threadIdx.x;
  const int lane = t & 63, w = t >> 6;
  const int row0 = blockIdx.x * 128;

  f32x4 acc[2][8];
#pragma unroll
  for (int fr = 0; fr < 2; ++fr)
#pragma unroll
    for (int fc = 0; fc < 8; ++fc) {
      acc[fr][fc][0] = 0.f; acc[fr][fc][1] = 0.f;
      acc[fr][fc][2] = 0.f; acc[fr][fc][3] = 0.f;
    }

  for (int k0 = 0; k0 < K2F; k0 += 32) {
    if (k0) __syncthreads();
#pragma unroll
    for (int it = 0; it < 2; ++it) {
      int cc = it * 256 + t;
      int r = cc >> 2, kc = (cc & 3) * 8;
      *(u16x8*)&As[r][kc] = *(const u16x8*)&xcat[(size_t)(row0 + r) * K2F + k0 + kc];
      *(u16x8*)&Bs[r][kc] = *(const u16x8*)&Wcb[(size_t)r * K2F + k0 + kc];
    }
    __syncthreads();

    const int frow = lane & 15;
    const int kc = (lane >> 4) * 8;
    short8 a0 = *(const short8*)&As[w * 32 + frow][kc];
    short8 a1 = *(const short8*)&As[w * 32 + 16 + frow][kc];
#pragma unroll
    for (int fc = 0; fc < 8; ++fc) {
      short8 b = *(const short8*)&Bs[fc * 16 + frow][kc];
      acc[0][fc] = __builtin_amdgcn_mfma_f32_16x16x32_bf16(a0, b, acc[0][fc], 0, 0, 0);
      acc[1][fc] = __builtin_amdgcn_mfma_f32_16x16x32_bf16(a1, b, acc[1][fc], 0, 0, 0);
    }
  }

  float bcv[8];
#pragma unroll
  for (int fc = 0; fc < 8; ++fc) bcv[fc] = bc[fc * 16 + (lane & 15)];
#pragma unroll
  for (int fr = 0; fr < 2; ++fr) {
#pragma unroll
    for (int q = 0; q < 4; ++q) {
      float x[8];
      float ss = 0.f;
#pragma unroll
      for (int fc = 0; fc < 8; ++fc) {
        x[fc] = lrelu(acc[fr][fc][q] + bcv[fc]);
        ss += x[fc] * x[fc];
      }
#pragma unroll
      for (int m = 8; m >= 1; m >>= 1) ss += __shfl_xor(ss, m, 64);
      float nrm = 1.f / fmaxf(sqrtf(ss), 1e-6f);
      int n = row0 + w * 32 + fr * 16 + (lane >> 4) * 4 + q;
#pragma unroll
      for (int fc = 0; fc < 8; ++fc) {
        int col = fc * 16 + (lane & 15);
        if (F32OUT) outf[(size_t)n * F + col] = x[fc] * nrm;
        else        outb[(size_t)n * F + col] = f2bf(x[fc] * nrm);
      }
    }
  }
}

extern "C" void kernel_launch(void* const* d_in, const int* in_sizes, int n_in,
                              void* d_out, int out_size, void* d_ws, size_t ws_size,
                              hipStream_t stream) {
  const int*   nid0     = (const int*)d_in[0];
  const int*   nid1     = (const int*)d_in[1];
  const int*   nid2     = (const int*)d_in[2];
  const float* content0 = (const float*)d_in[3];
  const float* content1 = (const float*)d_in[4];
  const float* content2 = (const float*)d_in[5];
  const int*   b0s      = (const int*)d_in[6];
  const int*   b0d      = (const int*)d_in[7];
  const int*   b1s      = (const int*)d_in[8];
  const int*   b1d      = (const int*)d_in[9];
  const float* emb      = (const float*)d_in[10];
  const float* Wp0      = (const float*)d_in[11];
  const float* bp0      = (const float*)d_in[12];
  const float* Wp1      = (const float*)d_in[13];
  const float* bp1      = (const float*)d_in[14];
  const float* Wp2      = (const float*)d_in[15];
  const float* bp2      = (const float*)d_in[16];
  const float* Wc0      = (const float*)d_in[17];
  const float* bc0      = (const float*)d_in[18];
  const float* Wc1      = (const float*)d_in[19];
  const float* bc1      = (const float*)d_in[20];

  u16* wsu = (u16*)d_ws;
  u16* h0b   = wsu;                               // N0*F bf16
  u16* xcat1 = h0b + (size_t)N0_ * F;             // N1*256 bf16 (h1 | xa1)
  u16* xcat2 = xcat1 + (size_t)N1_ * 2 * F;       // N2*256 bf16 (h2 | xa2)
  u16* h1nb  = xcat2 + (size_t)N2_ * 2 * F;       // N1*F bf16 (conv0 out)
  u16* Wpb0  = h1nb + (size_t)N1_ * F;            // F*CKP bf16 each
  u16* Wpb1  = Wpb0 + (size_t)F * CKP;
  u16* Wpb2  = Wpb1 + (size_t)F * CKP;
  u16* Wcb0  = Wpb2 + (size_t)F * CKP;            // F*K2F bf16 each
  u16* Wcb1  = Wcb0 + (size_t)F * K2F;
  int* deg0  = (int*)(Wcb1 + (size_t)F * K2F);    // N1 } zeroed together
  int* deg1  = deg0 + N1_;                        // N2 }
  int* csr0  = deg1 + N2_;                        // N1*CAP
  int* csr1  = csr0 + (size_t)N1_ * CAP;          // N2*CAP

  const int zn4 = (N1_ + N2_) / 4;
  zero_kernel<<<(zn4 + 255) / 256, 256, 0, stream>>>((float4*)deg0, zn4);

  build_csr<<<(E0_ + E1_ + 255) / 256, 256, 0, stream>>>(
      b0s, b0d, b1s, b1d, deg0, deg1, csr0, csr1);

  convert_all<<<(3 * F * CKP + 2 * F * K2F + 255) / 256, 256, 0, stream>>>(
      Wp0, Wp1, Wp2, Wc0, Wc1, Wpb0, Wpb1, Wpb2, Wcb0, Wcb1);

  embed_all<<<(N0_ + N1_ + N2_) / 256, 512, 0, stream>>>(
      content0, content1, content2, Wpb0, Wpb1, Wpb2,
      bp0, bp1, bp2, nid0, nid1, nid2, emb, h0b, xcat1, xcat2);

  gather_xa<<<N1_ / 4, 256, 0, stream>>>(h0b, csr0, deg0, xcat1);
  conv_mfma<0><<<N1_ / 128, 256, 0, stream>>>(xcat1, Wcb0, bc0, h1nb, nullptr);

  gather_xa<<<N2_ / 4, 256, 0, stream>>>(h1nb, csr1, deg1, xcat2);
  conv_mfma<1><<<N2_ / 128, 256, 0, stream>>>(xcat2, Wcb1, bc1, nullptr, (float*)d_out);
}